// Round 11
// baseline (190.663 us; speedup 1.0000x reference)
//
#include <hip/hip_runtime.h>
#include <math.h>

#define NJ 16
#define NV 778
#define M3 2334   // NV*3
#define S  8      // samples per block in k3a

typedef float f32x8  __attribute__((ext_vector_type(8)));
typedef float f32x16 __attribute__((ext_vector_type(16)));

__device__ __forceinline__ f32x8 splat8(float x) {
    f32x8 r = {x, x, x, x, x, x, x, x};
    return r;
}
// elementwise fused r = f*s + c  (all constant indices -> pure SSA)
__device__ __forceinline__ f32x8 fma8v(f32x8 f, float s, f32x8 c) {
    f32x8 r;
    r[0] = fmaf(f[0], s, c[0]); r[1] = fmaf(f[1], s, c[1]);
    r[2] = fmaf(f[2], s, c[2]); r[3] = fmaf(f[3], s, c[3]);
    r[4] = fmaf(f[4], s, c[4]); r[5] = fmaf(f[5], s, c[5]);
    r[6] = fmaf(f[6], s, c[6]); r[7] = fmaf(f[7], s, c[7]);
    return r;
}

// d_out layout (floats): verts [N*2334] | joints [N*48] | Rs [N*144]
// d_ws layout (floats):  A [N*192] | jpart [N*4*48]
// Pipeline: k0 -> k1 -> k2(A->ws) -> k3a(v_posed->verts) -> k4a(blend in place,
//           barrier-free) -> k4b(joint partials, barrier-free) -> k5(sum)
//
// LAUNCH-BOUNDS LESSON (R4, R8): second arg w empirically caps VGPR at 256/w
// on this toolchain (w=4 -> 64-VGPR cap -> catastrophic spill). Only (B, 1) is
// trustworthy (cap ~256). Control occupancy via register usage + grid.
// LATENCY LESSON (R9, R10): per-sample blocks with __syncthreads-separated
// short phases are latency-bound (~8 µs critical path vs 0.5 µs VALU). Prefer
// barrier-free one-thread-per-output kernels for the tail.

// ---------------- K0: SJ[b,j,c] = sum_v shapedirs[b,v,c]*Jreg[v,j]; b==10 -> vtemp
__global__ __launch_bounds__(64) void k0_prep(
    const float* __restrict__ shapedirs,
    const float* __restrict__ Jreg,
    const float* __restrict__ vtemp,
    float* __restrict__ SJJT)   // 528 floats
{
    int b = blockIdx.x / 16;    // 0..9 = shapedirs row, 10 = vtemp
    int j = blockIdx.x % 16;
    int t = threadIdx.x;
    const float* src = (b < 10) ? (shapedirs + (size_t)b * M3) : vtemp;
    float a0 = 0.f, a1 = 0.f, a2 = 0.f;
    for (int v = t; v < NV; v += 64) {
        float jr = Jreg[v * 16 + j];
        a0 = fmaf(src[v*3 + 0], jr, a0);
        a1 = fmaf(src[v*3 + 1], jr, a1);
        a2 = fmaf(src[v*3 + 2], jr, a2);
    }
#pragma unroll
    for (int m = 1; m < 64; m <<= 1) {
        a0 += __shfl_xor(a0, m);
        a1 += __shfl_xor(a1, m);
        a2 += __shfl_xor(a2, m);
    }
    if (t == 0) {
        int base = (b < 10) ? (b*48 + j*3) : (480 + j*3);
        SJJT[base + 0] = a0;
        SJJT[base + 1] = a1;
        SJJT[base + 2] = a2;
    }
}

// ---------------- K1: Rodrigues, one thread per (n, joint)
__global__ __launch_bounds__(256) void k1_rodrigues(
    const float* __restrict__ theta, float* __restrict__ RsOut, int N)
{
    int idx = blockIdx.x * 256 + threadIdx.x;
    if (idx >= N * NJ) return;
    int n = idx >> 4;
    int j = idx & 15;
    float t0 = theta[n*48 + j*3 + 0];
    float t1 = theta[n*48 + j*3 + 1];
    float t2 = theta[n*48 + j*3 + 2];
    const float eps = 1e-8f;
    float a0 = t0 + eps, a1 = t1 + eps, a2 = t2 + eps;
    float angle = sqrtf(a0*a0 + a1*a1 + a2*a2);
    float inv  = 1.0f / angle;
    float half = 0.5f * angle;
    float sh = sinf(half), chh = cosf(half);
    float qw = chh;
    float qx = sh * t0 * inv;
    float qy = sh * t1 * inv;
    float qz = sh * t2 * inv;
    float qn = 1.0f / sqrtf(qw*qw + qx*qx + qy*qy + qz*qz);
    qw *= qn; qx *= qn; qy *= qn; qz *= qn;
    float w2=qw*qw, x2=qx*qx, y2=qy*qy, z2=qz*qz;
    float wx=qw*qx, wy=qw*qy, wz=qw*qz;
    float xy=qx*qy, xz=qx*qz, yz=qy*qz;
    float* R = RsOut + (size_t)idx * 9;
    R[0] = w2 + x2 - y2 - z2;
    R[1] = 2.f*(xy - wz);
    R[2] = 2.f*(wy + xz);
    R[3] = 2.f*(wz + xy);
    R[4] = w2 - x2 + y2 - z2;
    R[5] = 2.f*(yz - wx);
    R[6] = 2.f*(xz - wy);
    R[7] = 2.f*(wx + yz);
    R[8] = w2 - x2 - y2 + z2;
}

// ---------------- K2: kinematic chain -> A into d_ws (192 floats / sample)
__global__ __launch_bounds__(64) void k2_chain(
    const float* __restrict__ beta,
    const float* __restrict__ Rs,     // d_out Rs region
    const float* __restrict__ SJJT,   // 528 floats
    float* __restrict__ Aws,          // d_ws; A[n] at n*192
    int N)
{
    __shared__ float sS[528];
    for (int i = threadIdx.x; i < 528; i += 64) sS[i] = SJJT[i];
    __syncthreads();
    int gid = blockIdx.x * 64 + threadIdx.x;
    if (gid >= N * 5) return;
    int n  = gid / 5;
    int ch = gid % 5;

    float b[10];
#pragma unroll
    for (int i = 0; i < 10; ++i) b[i] = beta[n*10 + i];

    int jidx[4];
    jidx[0] = 0; jidx[1] = ch*3 + 1; jidx[2] = ch*3 + 2; jidx[3] = ch*3 + 3;
    float J[4][3];
#pragma unroll
    for (int q = 0; q < 4; ++q) {
        int j = jidx[q];
#pragma unroll
        for (int c = 0; c < 3; ++c) {
            float acc = sS[480 + j*3 + c];
#pragma unroll
            for (int qq = 0; qq < 10; ++qq)
                acc = fmaf(b[qq], sS[qq*48 + j*3 + c], acc);
            J[q][c] = acc;
        }
    }

    const float* Rn = Rs + (size_t)n * 144;
    float* An = Aws + (size_t)n * 192;

    float GpR[9], Gpt[3];
#pragma unroll
    for (int r = 0; r < 3; ++r) {
        GpR[r*3+0] =  Rn[r*3+0];
        GpR[r*3+1] = -Rn[r*3+1];
        GpR[r*3+2] = -Rn[r*3+2];
    }
    Gpt[0] = J[0][0]; Gpt[1] = J[0][1]; Gpt[2] = J[0][2];

    if (ch == 0) {
#pragma unroll
        for (int r = 0; r < 3; ++r) {
            float rel = GpR[r*3+0]*J[0][0] + GpR[r*3+1]*J[0][1] + GpR[r*3+2]*J[0][2];
            An[r*4 + 0] = GpR[r*3+0];
            An[r*4 + 1] = GpR[r*3+1];
            An[r*4 + 2] = GpR[r*3+2];
            An[r*4 + 3] = Gpt[r] - rel;
        }
    }

#pragma unroll
    for (int st = 0; st < 3; ++st) {
        int i = jidx[st+1];
        const float* Ri = Rn + (size_t)i * 9;
        float t0 = J[st+1][0] - J[st][0];
        float t1 = J[st+1][1] - J[st][1];
        float t2 = J[st+1][2] - J[st][2];
        float GR[9], Gt[3];
#pragma unroll
        for (int r = 0; r < 3; ++r) {
#pragma unroll
            for (int c = 0; c < 3; ++c)
                GR[r*3+c] = GpR[r*3+0]*Ri[c] + GpR[r*3+1]*Ri[3+c] + GpR[r*3+2]*Ri[6+c];
            Gt[r] = GpR[r*3+0]*t0 + GpR[r*3+1]*t1 + GpR[r*3+2]*t2 + Gpt[r];
        }
#pragma unroll
        for (int r = 0; r < 3; ++r) {
            float rel = GR[r*3+0]*J[st+1][0] + GR[r*3+1]*J[st+1][1] + GR[r*3+2]*J[st+1][2];
            An[i*12 + r*4 + 0] = GR[r*3+0];
            An[i*12 + r*4 + 1] = GR[r*3+1];
            An[i*12 + r*4 + 2] = GR[r*3+2];
            An[i*12 + r*4 + 3] = Gt[r] - rel;
        }
#pragma unroll
        for (int r = 0; r < 9; ++r) GpR[r] = GR[r];
        Gpt[0] = Gt[0]; Gpt[1] = Gt[1]; Gpt[2] = Gt[2];
    }
}

// ---------------- K3a: GEMM only. Block = 8 samples x 512-vert half; 256 thr x
// 2 vert-slots. acc = 6 f32x8 = 48 VGPR + temps ~= 90 total. (256,1): no spill.
#define GSTEP(rowptr, fk) { \
    f32x8 fv_ = *(const f32x8*)&sF[(fk)][0]; \
    const float* r0_ = (rowptr) + 3*v0; \
    const float* r1_ = (rowptr) + 3*c1; \
    float x0_=r0_[0], y0_=r0_[1], z0_=r0_[2]; \
    float x1_=r1_[0], y1_=r1_[1], z1_=r1_[2]; \
    ax0=fma8v(fv_,x0_,ax0); ay0=fma8v(fv_,y0_,ay0); az0=fma8v(fv_,z0_,az0); \
    ax1=fma8v(fv_,x1_,ax1); ay1=fma8v(fv_,y1_,ay1); az1=fma8v(fv_,z1_,az1); }

#define STORE_SLOT(s_, ii, vv) if ((vv) < NV) { \
    float* o_ = vposed + (size_t)(n0 + s_)*M3 + (size_t)(vv)*3; \
    o_[0] = ax##ii[s_]; o_[1] = ay##ii[s_]; o_[2] = az##ii[s_]; }

#define STORE_S(s_) { STORE_SLOT(s_,0,v0) STORE_SLOT(s_,1,v1) }

__global__ __launch_bounds__(256, 1) void k3a_gemm(
    const float* __restrict__ beta,
    const float* __restrict__ posedirs,
    const float* __restrict__ shapedirs,
    const float* __restrict__ vtemp,
    const float* __restrict__ Rs,
    float* __restrict__ vposed,         // verts region
    int N)
{
    __shared__ __attribute__((aligned(32))) float sF[145][S]; // 10 beta + 135 posefeat
    const int n0   = blockIdx.x * S;
    const int half = blockIdx.y;
    const int tid  = threadIdx.x;

    // stage features: k<10 -> beta[k]; k>=10 -> Rs[9 + (k-10)] - I
    for (int idx = tid; idx < 145 * S; idx += 256) {
        int k = idx / S, s = idx % S;
        float val;
        if (k < 10) {
            val = beta[(size_t)(n0+s)*10 + k];
        } else {
            int kk = k - 10;
            int rr = kk % 9;
            val = Rs[(size_t)(n0+s)*144 + 9 + kk];
            if ((rr & 3) == 0) val -= 1.f;   // rr in {0,4,8}
        }
        sF[k][s] = val;
    }
    __syncthreads();

    const int v0 = half * 512 + tid;            // 0..767, always < 778
    const int v1 = v0 + 256;                    // may exceed NV when half==1
    const int c1 = (v1 < NV) ? v1 : (NV - 1);   // clamp: no divergent compute

    f32x8 ax0 = splat8(vtemp[v0*3+0]), ay0 = splat8(vtemp[v0*3+1]), az0 = splat8(vtemp[v0*3+2]);
    f32x8 ax1 = splat8(vtemp[c1*3+0]), ay1 = splat8(vtemp[c1*3+1]), az1 = splat8(vtemp[c1*3+2]);

    for (int k = 0; k < 10; ++k)  { GSTEP(shapedirs + (size_t)k*M3, k) }
    for (int k = 0; k < 135; ++k) { GSTEP(posedirs  + (size_t)k*M3, k + 10) }

    STORE_S(0) STORE_S(1) STORE_S(2) STORE_S(3)
    STORE_S(4) STORE_S(5) STORE_S(6) STORE_S(7)
}

// ---------------- K4a: LBS blend, barrier-free, one thread per (n, v).
// w: 64B/lane coalesced; A: wave-broadcast from L2 (3.1 MB, L2-resident);
// verts updated in place (same-thread read->write). VGPR ~45 -> high occupancy.
__global__ __launch_bounds__(256, 1) void k4a_blend(
    const float* __restrict__ Aws,      // d_ws
    const float* __restrict__ weights,
    float* verts,                       // in-place
    int N)
{
    int gid = blockIdx.x * 256 + threadIdx.x;
    if (gid >= N * NV) return;
    int n = gid / NV;
    int v = gid - n * NV;

    float* vp = verts + (size_t)gid * 3;
    float vx = vp[0], vy = vp[1], vz = vp[2];
    f32x16 w = *reinterpret_cast<const f32x16*>(&weights[(size_t)v * 16]);
    const float4* A4 = reinterpret_cast<const float4*>(Aws + (size_t)n * 192);

    float ox = 0.f, oy = 0.f, oz = 0.f;
#define BJA(j_) { \
    float4 A0 = A4[(j_)*3+0], A1 = A4[(j_)*3+1], A2 = A4[(j_)*3+2]; \
    float X_ = fmaf(A0.x,vx, fmaf(A0.y,vy, fmaf(A0.z,vz, A0.w))); \
    float Y_ = fmaf(A1.x,vx, fmaf(A1.y,vy, fmaf(A1.z,vz, A1.w))); \
    float Z_ = fmaf(A2.x,vx, fmaf(A2.y,vy, fmaf(A2.z,vz, A2.w))); \
    ox = fmaf(w[j_], X_, ox); oy = fmaf(w[j_], Y_, oy); oz = fmaf(w[j_], Z_, oz); }
    BJA(0)  BJA(1)  BJA(2)  BJA(3)  BJA(4)  BJA(5)  BJA(6)  BJA(7)
    BJA(8)  BJA(9)  BJA(10) BJA(11) BJA(12) BJA(13) BJA(14) BJA(15)
#undef BJA

    vp[0] = ox; vp[1] = oy; vp[2] = oz;
}

// ---------------- K4b: joint partials, barrier-free. One thread per
// (n, chunk, j), j fastest (coalesced Jreg; verts broadcast across j-lanes).
// 4 chunks of <=195 verts -> jpart[n*192 + chunk*48 + j*3 + c].
__global__ __launch_bounds__(256, 1) void k4b_joints(
    const float* __restrict__ verts,
    const float* __restrict__ Jreg,
    float* __restrict__ jpart,          // d_ws + N*192
    int N)
{
    int gid = blockIdx.x * 256 + threadIdx.x;   // total N*4*16
    if (gid >= N * 64) return;
    int j  = gid & 15;
    int c4 = (gid >> 4) & 3;
    int n  = gid >> 6;

    int vbeg = c4 * 195;
    int vend = vbeg + 195; if (vend > NV) vend = NV;

    const float* vp = verts + (size_t)n * M3;
    float a0 = 0.f, a1 = 0.f, a2 = 0.f;
#pragma unroll 4
    for (int v = vbeg; v < vend; ++v) {
        float jr = Jreg[(size_t)v * 16 + j];
        float x = vp[v*3 + 0], y = vp[v*3 + 1], z = vp[v*3 + 2];
        a0 = fmaf(jr, x, a0);
        a1 = fmaf(jr, y, a1);
        a2 = fmaf(jr, z, a2);
    }
    float* o = jpart + (size_t)n * 192 + c4 * 48 + j * 3;
    o[0] = a0; o[1] = a1; o[2] = a2;
}

// ---------------- K5: joints[n*48+r] = sum_c4 jpart[n*192 + c4*48 + r]
__global__ __launch_bounds__(256) void k5_joint_sum(
    const float* __restrict__ jpart, float* __restrict__ joints, int N)
{
    int i = blockIdx.x * 256 + threadIdx.x;     // N*48
    if (i >= N * 48) return;
    int n = i / 48;
    int r = i - n * 48;
    const float* p = jpart + (size_t)n * 192 + r;
    joints[i] = p[0] + p[48] + p[96] + p[144];
}

extern "C" void kernel_launch(void* const* d_in, const int* in_sizes, int n_in,
                              void* d_out, int out_size, void* d_ws, size_t ws_size,
                              hipStream_t stream)
{
    const float* beta   = (const float*)d_in[0];
    const float* theta  = (const float*)d_in[1];
    const float* vtemp  = (const float*)d_in[2];
    const float* shaped = (const float*)d_in[3];
    const float* Jreg   = (const float*)d_in[4];
    const float* posed  = (const float*)d_in[5];
    const float* wts    = (const float*)d_in[6];
    float* out = (float*)d_out;
    const int N = in_sizes[0] / 10;   // 4096

    float* verts  = out;                            // N*2334
    float* joints = out + (size_t)N * M3;           // N*48
    float* RsOut  = joints + (size_t)N * 48;        // N*144
    float* Aws    = (float*)d_ws;                   // N*192 floats = 3.1 MB
    float* jpart  = Aws + (size_t)N * 192;          // N*192 floats = 3.1 MB

    k0_prep<<<176, 64, 0, stream>>>(shaped, Jreg, vtemp, joints);
    k1_rodrigues<<<(N*NJ + 255)/256, 256, 0, stream>>>(theta, RsOut, N);
    k2_chain<<<(N*5 + 63)/64, 64, 0, stream>>>(beta, RsOut, joints, Aws, N);
    k3a_gemm<<<dim3(N/S, 2), 256, 0, stream>>>(beta, posed, shaped, vtemp, RsOut, verts, N);
    k4a_blend<<<(N*NV + 255)/256, 256, 0, stream>>>(Aws, wts, verts, N);
    k4b_joints<<<(N*64 + 255)/256, 256, 0, stream>>>(verts, Jreg, jpart, N);
    k5_joint_sum<<<(N*48 + 255)/256, 256, 0, stream>>>(jpart, joints, N);
}

// Round 12
// 175.728 us; speedup vs baseline: 1.0850x; 1.0850x over previous
//
#include <hip/hip_runtime.h>
#include <math.h>

#define NJ 16
#define NV 778
#define M3 2334   // NV*3
#define S  8      // samples per block in k3a

typedef float f32x8  __attribute__((ext_vector_type(8)));
typedef float f32x16 __attribute__((ext_vector_type(16)));

__device__ __forceinline__ f32x8 splat8(float x) {
    f32x8 r = {x, x, x, x, x, x, x, x};
    return r;
}
// elementwise fused r = f*s + c  (all constant indices -> pure SSA)
__device__ __forceinline__ f32x8 fma8v(f32x8 f, float s, f32x8 c) {
    f32x8 r;
    r[0] = fmaf(f[0], s, c[0]); r[1] = fmaf(f[1], s, c[1]);
    r[2] = fmaf(f[2], s, c[2]); r[3] = fmaf(f[3], s, c[3]);
    r[4] = fmaf(f[4], s, c[4]); r[5] = fmaf(f[5], s, c[5]);
    r[6] = fmaf(f[6], s, c[6]); r[7] = fmaf(f[7], s, c[7]);
    return r;
}

// d_out layout (floats): verts [N*2334] | joints [N*48] | Rs [N*144]
// d_ws layout (floats):  A [N*192] | jpart [N*4*48]
// Pipeline: k0 -> k1 -> k2(A->ws) -> k3a(v_posed->verts) -> k4a(blend in place,
//           barrier-free, 4 verts/thread) -> k4b(joint partials) -> k5(sum)
//
// LAUNCH-BOUNDS LESSON (R4, R8): second arg w empirically caps VGPR at 256/w
// (w=4 -> 64-VGPR cap -> catastrophic spill). Only (B, 1) is trustworthy.
// LATENCY LESSON (R9-R11): short dependent load->compute rounds serialize on
// L2 latency; amortize uniform loads over more per-thread compute and leave
// VGPR headroom so the compiler can prefetch the next round.

// ---------------- K0: SJ[b,j,c] = sum_v shapedirs[b,v,c]*Jreg[v,j]; b==10 -> vtemp
__global__ __launch_bounds__(64) void k0_prep(
    const float* __restrict__ shapedirs,
    const float* __restrict__ Jreg,
    const float* __restrict__ vtemp,
    float* __restrict__ SJJT)   // 528 floats
{
    int b = blockIdx.x / 16;    // 0..9 = shapedirs row, 10 = vtemp
    int j = blockIdx.x % 16;
    int t = threadIdx.x;
    const float* src = (b < 10) ? (shapedirs + (size_t)b * M3) : vtemp;
    float a0 = 0.f, a1 = 0.f, a2 = 0.f;
    for (int v = t; v < NV; v += 64) {
        float jr = Jreg[v * 16 + j];
        a0 = fmaf(src[v*3 + 0], jr, a0);
        a1 = fmaf(src[v*3 + 1], jr, a1);
        a2 = fmaf(src[v*3 + 2], jr, a2);
    }
#pragma unroll
    for (int m = 1; m < 64; m <<= 1) {
        a0 += __shfl_xor(a0, m);
        a1 += __shfl_xor(a1, m);
        a2 += __shfl_xor(a2, m);
    }
    if (t == 0) {
        int base = (b < 10) ? (b*48 + j*3) : (480 + j*3);
        SJJT[base + 0] = a0;
        SJJT[base + 1] = a1;
        SJJT[base + 2] = a2;
    }
}

// ---------------- K1: Rodrigues, one thread per (n, joint)
__global__ __launch_bounds__(256) void k1_rodrigues(
    const float* __restrict__ theta, float* __restrict__ RsOut, int N)
{
    int idx = blockIdx.x * 256 + threadIdx.x;
    if (idx >= N * NJ) return;
    int n = idx >> 4;
    int j = idx & 15;
    float t0 = theta[n*48 + j*3 + 0];
    float t1 = theta[n*48 + j*3 + 1];
    float t2 = theta[n*48 + j*3 + 2];
    const float eps = 1e-8f;
    float a0 = t0 + eps, a1 = t1 + eps, a2 = t2 + eps;
    float angle = sqrtf(a0*a0 + a1*a1 + a2*a2);
    float inv  = 1.0f / angle;
    float half = 0.5f * angle;
    float sh = sinf(half), chh = cosf(half);
    float qw = chh;
    float qx = sh * t0 * inv;
    float qy = sh * t1 * inv;
    float qz = sh * t2 * inv;
    float qn = 1.0f / sqrtf(qw*qw + qx*qx + qy*qy + qz*qz);
    qw *= qn; qx *= qn; qy *= qn; qz *= qn;
    float w2=qw*qw, x2=qx*qx, y2=qy*qy, z2=qz*qz;
    float wx=qw*qx, wy=qw*qy, wz=qw*qz;
    float xy=qx*qy, xz=qx*qz, yz=qy*qz;
    float* R = RsOut + (size_t)idx * 9;
    R[0] = w2 + x2 - y2 - z2;
    R[1] = 2.f*(xy - wz);
    R[2] = 2.f*(wy + xz);
    R[3] = 2.f*(wz + xy);
    R[4] = w2 - x2 + y2 - z2;
    R[5] = 2.f*(yz - wx);
    R[6] = 2.f*(xz - wy);
    R[7] = 2.f*(wx + yz);
    R[8] = w2 - x2 - y2 + z2;
}

// ---------------- K2: kinematic chain -> A into d_ws (192 floats / sample)
__global__ __launch_bounds__(64) void k2_chain(
    const float* __restrict__ beta,
    const float* __restrict__ Rs,     // d_out Rs region
    const float* __restrict__ SJJT,   // 528 floats
    float* __restrict__ Aws,          // d_ws; A[n] at n*192
    int N)
{
    __shared__ float sS[528];
    for (int i = threadIdx.x; i < 528; i += 64) sS[i] = SJJT[i];
    __syncthreads();
    int gid = blockIdx.x * 64 + threadIdx.x;
    if (gid >= N * 5) return;
    int n  = gid / 5;
    int ch = gid % 5;

    float b[10];
#pragma unroll
    for (int i = 0; i < 10; ++i) b[i] = beta[n*10 + i];

    int jidx[4];
    jidx[0] = 0; jidx[1] = ch*3 + 1; jidx[2] = ch*3 + 2; jidx[3] = ch*3 + 3;
    float J[4][3];
#pragma unroll
    for (int q = 0; q < 4; ++q) {
        int j = jidx[q];
#pragma unroll
        for (int c = 0; c < 3; ++c) {
            float acc = sS[480 + j*3 + c];
#pragma unroll
            for (int qq = 0; qq < 10; ++qq)
                acc = fmaf(b[qq], sS[qq*48 + j*3 + c], acc);
            J[q][c] = acc;
        }
    }

    const float* Rn = Rs + (size_t)n * 144;
    float* An = Aws + (size_t)n * 192;

    float GpR[9], Gpt[3];
#pragma unroll
    for (int r = 0; r < 3; ++r) {
        GpR[r*3+0] =  Rn[r*3+0];
        GpR[r*3+1] = -Rn[r*3+1];
        GpR[r*3+2] = -Rn[r*3+2];
    }
    Gpt[0] = J[0][0]; Gpt[1] = J[0][1]; Gpt[2] = J[0][2];

    if (ch == 0) {
#pragma unroll
        for (int r = 0; r < 3; ++r) {
            float rel = GpR[r*3+0]*J[0][0] + GpR[r*3+1]*J[0][1] + GpR[r*3+2]*J[0][2];
            An[r*4 + 0] = GpR[r*3+0];
            An[r*4 + 1] = GpR[r*3+1];
            An[r*4 + 2] = GpR[r*3+2];
            An[r*4 + 3] = Gpt[r] - rel;
        }
    }

#pragma unroll
    for (int st = 0; st < 3; ++st) {
        int i = jidx[st+1];
        const float* Ri = Rn + (size_t)i * 9;
        float t0 = J[st+1][0] - J[st][0];
        float t1 = J[st+1][1] - J[st][1];
        float t2 = J[st+1][2] - J[st][2];
        float GR[9], Gt[3];
#pragma unroll
        for (int r = 0; r < 3; ++r) {
#pragma unroll
            for (int c = 0; c < 3; ++c)
                GR[r*3+c] = GpR[r*3+0]*Ri[c] + GpR[r*3+1]*Ri[3+c] + GpR[r*3+2]*Ri[6+c];
            Gt[r] = GpR[r*3+0]*t0 + GpR[r*3+1]*t1 + GpR[r*3+2]*t2 + Gpt[r];
        }
#pragma unroll
        for (int r = 0; r < 3; ++r) {
            float rel = GR[r*3+0]*J[st+1][0] + GR[r*3+1]*J[st+1][1] + GR[r*3+2]*J[st+1][2];
            An[i*12 + r*4 + 0] = GR[r*3+0];
            An[i*12 + r*4 + 1] = GR[r*3+1];
            An[i*12 + r*4 + 2] = GR[r*3+2];
            An[i*12 + r*4 + 3] = Gt[r] - rel;
        }
#pragma unroll
        for (int r = 0; r < 9; ++r) GpR[r] = GR[r];
        Gpt[0] = Gt[0]; Gpt[1] = Gt[1]; Gpt[2] = Gt[2];
    }
}

// ---------------- K3a: GEMM only. Block = 8 samples x 512-vert half; 256 thr x
// 2 vert-slots. acc = 6 f32x8 = 48 VGPR + temps ~= 90 total. (256,1): no spill.
#define GSTEP(rowptr, fk) { \
    f32x8 fv_ = *(const f32x8*)&sF[(fk)][0]; \
    const float* r0_ = (rowptr) + 3*v0; \
    const float* r1_ = (rowptr) + 3*c1; \
    float x0_=r0_[0], y0_=r0_[1], z0_=r0_[2]; \
    float x1_=r1_[0], y1_=r1_[1], z1_=r1_[2]; \
    ax0=fma8v(fv_,x0_,ax0); ay0=fma8v(fv_,y0_,ay0); az0=fma8v(fv_,z0_,az0); \
    ax1=fma8v(fv_,x1_,ax1); ay1=fma8v(fv_,y1_,ay1); az1=fma8v(fv_,z1_,az1); }

#define STORE_SLOT(s_, ii, vv) if ((vv) < NV) { \
    float* o_ = vposed + (size_t)(n0 + s_)*M3 + (size_t)(vv)*3; \
    o_[0] = ax##ii[s_]; o_[1] = ay##ii[s_]; o_[2] = az##ii[s_]; }

#define STORE_S(s_) { STORE_SLOT(s_,0,v0) STORE_SLOT(s_,1,v1) }

__global__ __launch_bounds__(256, 1) void k3a_gemm(
    const float* __restrict__ beta,
    const float* __restrict__ posedirs,
    const float* __restrict__ shapedirs,
    const float* __restrict__ vtemp,
    const float* __restrict__ Rs,
    float* __restrict__ vposed,         // verts region
    int N)
{
    __shared__ __attribute__((aligned(32))) float sF[145][S]; // 10 beta + 135 posefeat
    const int n0   = blockIdx.x * S;
    const int half = blockIdx.y;
    const int tid  = threadIdx.x;

    // stage features: k<10 -> beta[k]; k>=10 -> Rs[9 + (k-10)] - I
    for (int idx = tid; idx < 145 * S; idx += 256) {
        int k = idx / S, s = idx % S;
        float val;
        if (k < 10) {
            val = beta[(size_t)(n0+s)*10 + k];
        } else {
            int kk = k - 10;
            int rr = kk % 9;
            val = Rs[(size_t)(n0+s)*144 + 9 + kk];
            if ((rr & 3) == 0) val -= 1.f;   // rr in {0,4,8}
        }
        sF[k][s] = val;
    }
    __syncthreads();

    const int v0 = half * 512 + tid;            // 0..767, always < 778
    const int v1 = v0 + 256;                    // may exceed NV when half==1
    const int c1 = (v1 < NV) ? v1 : (NV - 1);   // clamp: no divergent compute

    f32x8 ax0 = splat8(vtemp[v0*3+0]), ay0 = splat8(vtemp[v0*3+1]), az0 = splat8(vtemp[v0*3+2]);
    f32x8 ax1 = splat8(vtemp[c1*3+0]), ay1 = splat8(vtemp[c1*3+1]), az1 = splat8(vtemp[c1*3+2]);

    for (int k = 0; k < 10; ++k)  { GSTEP(shapedirs + (size_t)k*M3, k) }
    for (int k = 0; k < 135; ++k) { GSTEP(posedirs  + (size_t)k*M3, k + 10) }

    STORE_S(0) STORE_S(1) STORE_S(2) STORE_S(3)
    STORE_S(4) STORE_S(5) STORE_S(6) STORE_S(7)
}

// ---------------- K4a: LBS blend, barrier-free, 4 verts per thread (same n).
// A-loads (wave-uniform, L2) amortized 4x: per j-round 3 loads cover 48 FMA,
// and ~120 VGPR leaves room for next-round prefetch. verts via float2
// (base n*9336 = 0 mod 8, quad offset 48q = 0 mod 16 -> 8B align guaranteed).
__global__ __launch_bounds__(256, 1) void k4a_blend(
    const float* __restrict__ Aws,      // d_ws
    const float* __restrict__ weights,
    float* verts,                       // in-place
    int N)
{
    const int NQ = 195;                 // ceil(778/4)
    int gid = blockIdx.x * 256 + threadIdx.x;
    if (gid >= N * NQ) return;
    int n = gid / NQ;
    int q = gid - n * NQ;
    int vb = q * 4;                     // first vert of quad
    const bool full = (vb + 4 <= NV);   // quad 194: verts 776,777 only

    float* vp = verts + (size_t)n * M3 + (size_t)vb * 3;   // 8B-aligned
    const float2* vp2 = reinterpret_cast<const float2*>(vp);

    // load 12 floats (4 verts x xyz); guard the tail quad
    float2 p0 = vp2[0], p1 = vp2[1], p2 = vp2[2];
    float2 p3 = {0.f, 0.f}, p4 = {0.f, 0.f}, p5 = {0.f, 0.f};
    if (full) { p3 = vp2[3]; p4 = vp2[4]; p5 = vp2[5]; }
    float x0 = p0.x, y0 = p0.y, z0 = p1.x;
    float x1 = p1.y, y1 = p2.x, z1 = p2.y;
    float x2 = p3.x, y2 = p3.y, z2 = p4.x;
    float x3 = p4.y, y3 = p5.x, z3 = p5.y;

    const int c1v = (vb+1 < NV) ? vb+1 : NV-1;
    const int c2v = (vb+2 < NV) ? vb+2 : NV-1;
    const int c3v = (vb+3 < NV) ? vb+3 : NV-1;
    f32x16 w0 = *reinterpret_cast<const f32x16*>(&weights[(size_t)vb  * 16]);
    f32x16 w1 = *reinterpret_cast<const f32x16*>(&weights[(size_t)c1v * 16]);
    f32x16 w2 = *reinterpret_cast<const f32x16*>(&weights[(size_t)c2v * 16]);
    f32x16 w3 = *reinterpret_cast<const f32x16*>(&weights[(size_t)c3v * 16]);

    const float4* A4 = reinterpret_cast<const float4*>(Aws + (size_t)n * 192);

    float o0x=0.f,o0y=0.f,o0z=0.f, o1x=0.f,o1y=0.f,o1z=0.f;
    float o2x=0.f,o2y=0.f,o2z=0.f, o3x=0.f,o3y=0.f,o3z=0.f;

#define BJA4(j_) { \
    float4 A0 = A4[(j_)*3+0], A1 = A4[(j_)*3+1], A2 = A4[(j_)*3+2]; \
    float X,Y,Z; \
    X = fmaf(A0.x,x0, fmaf(A0.y,y0, fmaf(A0.z,z0, A0.w))); \
    Y = fmaf(A1.x,x0, fmaf(A1.y,y0, fmaf(A1.z,z0, A1.w))); \
    Z = fmaf(A2.x,x0, fmaf(A2.y,y0, fmaf(A2.z,z0, A2.w))); \
    o0x = fmaf(w0[j_], X, o0x); o0y = fmaf(w0[j_], Y, o0y); o0z = fmaf(w0[j_], Z, o0z); \
    X = fmaf(A0.x,x1, fmaf(A0.y,y1, fmaf(A0.z,z1, A0.w))); \
    Y = fmaf(A1.x,x1, fmaf(A1.y,y1, fmaf(A1.z,z1, A1.w))); \
    Z = fmaf(A2.x,x1, fmaf(A2.y,y1, fmaf(A2.z,z1, A2.w))); \
    o1x = fmaf(w1[j_], X, o1x); o1y = fmaf(w1[j_], Y, o1y); o1z = fmaf(w1[j_], Z, o1z); \
    X = fmaf(A0.x,x2, fmaf(A0.y,y2, fmaf(A0.z,z2, A0.w))); \
    Y = fmaf(A1.x,x2, fmaf(A1.y,y2, fmaf(A1.z,z2, A1.w))); \
    Z = fmaf(A2.x,x2, fmaf(A2.y,y2, fmaf(A2.z,z2, A2.w))); \
    o2x = fmaf(w2[j_], X, o2x); o2y = fmaf(w2[j_], Y, o2y); o2z = fmaf(w2[j_], Z, o2z); \
    X = fmaf(A0.x,x3, fmaf(A0.y,y3, fmaf(A0.z,z3, A0.w))); \
    Y = fmaf(A1.x,x3, fmaf(A1.y,y3, fmaf(A1.z,z3, A1.w))); \
    Z = fmaf(A2.x,x3, fmaf(A2.y,y3, fmaf(A2.z,z3, A2.w))); \
    o3x = fmaf(w3[j_], X, o3x); o3y = fmaf(w3[j_], Y, o3y); o3z = fmaf(w3[j_], Z, o3z); }

    BJA4(0)  BJA4(1)  BJA4(2)  BJA4(3)  BJA4(4)  BJA4(5)  BJA4(6)  BJA4(7)
    BJA4(8)  BJA4(9)  BJA4(10) BJA4(11) BJA4(12) BJA4(13) BJA4(14) BJA4(15)
#undef BJA4

    float2* op2 = reinterpret_cast<float2*>(vp);
    float2 q0; q0.x = o0x; q0.y = o0y;
    float2 q1; q1.x = o0z; q1.y = o1x;
    float2 q2; q2.x = o1y; q2.y = o1z;
    op2[0] = q0; op2[1] = q1; op2[2] = q2;
    if (full) {
        float2 q3; q3.x = o2x; q3.y = o2y;
        float2 q4; q4.x = o2z; q4.y = o3x;
        float2 q5; q5.x = o3y; q5.y = o3z;
        op2[3] = q3; op2[4] = q4; op2[5] = q5;
    }
}

// ---------------- K4b: joint partials, barrier-free. One thread per
// (n, chunk, j), j fastest (coalesced Jreg; verts broadcast across j-lanes).
// 4 chunks of <=195 verts -> jpart[n*192 + chunk*48 + j*3 + c].
__global__ __launch_bounds__(256, 1) void k4b_joints(
    const float* __restrict__ verts,
    const float* __restrict__ Jreg,
    float* __restrict__ jpart,          // d_ws + N*192
    int N)
{
    int gid = blockIdx.x * 256 + threadIdx.x;   // total N*4*16
    if (gid >= N * 64) return;
    int j  = gid & 15;
    int c4 = (gid >> 4) & 3;
    int n  = gid >> 6;

    int vbeg = c4 * 195;
    int vend = vbeg + 195; if (vend > NV) vend = NV;

    const float* vp = verts + (size_t)n * M3;
    float a0 = 0.f, a1 = 0.f, a2 = 0.f;
#pragma unroll 4
    for (int v = vbeg; v < vend; ++v) {
        float jr = Jreg[(size_t)v * 16 + j];
        float x = vp[v*3 + 0], y = vp[v*3 + 1], z = vp[v*3 + 2];
        a0 = fmaf(jr, x, a0);
        a1 = fmaf(jr, y, a1);
        a2 = fmaf(jr, z, a2);
    }
    float* o = jpart + (size_t)n * 192 + c4 * 48 + j * 3;
    o[0] = a0; o[1] = a1; o[2] = a2;
}

// ---------------- K5: joints[n*48+r] = sum_c4 jpart[n*192 + c4*48 + r]
__global__ __launch_bounds__(256) void k5_joint_sum(
    const float* __restrict__ jpart, float* __restrict__ joints, int N)
{
    int i = blockIdx.x * 256 + threadIdx.x;     // N*48
    if (i >= N * 48) return;
    int n = i / 48;
    int r = i - n * 48;
    const float* p = jpart + (size_t)n * 192 + r;
    joints[i] = p[0] + p[48] + p[96] + p[144];
}

extern "C" void kernel_launch(void* const* d_in, const int* in_sizes, int n_in,
                              void* d_out, int out_size, void* d_ws, size_t ws_size,
                              hipStream_t stream)
{
    const float* beta   = (const float*)d_in[0];
    const float* theta  = (const float*)d_in[1];
    const float* vtemp  = (const float*)d_in[2];
    const float* shaped = (const float*)d_in[3];
    const float* Jreg   = (const float*)d_in[4];
    const float* posed  = (const float*)d_in[5];
    const float* wts    = (const float*)d_in[6];
    float* out = (float*)d_out;
    const int N = in_sizes[0] / 10;   // 4096

    float* verts  = out;                            // N*2334
    float* joints = out + (size_t)N * M3;           // N*48
    float* RsOut  = joints + (size_t)N * 48;        // N*144
    float* Aws    = (float*)d_ws;                   // N*192 floats = 3.1 MB
    float* jpart  = Aws + (size_t)N * 192;          // N*192 floats = 3.1 MB

    k0_prep<<<176, 64, 0, stream>>>(shaped, Jreg, vtemp, joints);
    k1_rodrigues<<<(N*NJ + 255)/256, 256, 0, stream>>>(theta, RsOut, N);
    k2_chain<<<(N*5 + 63)/64, 64, 0, stream>>>(beta, RsOut, joints, Aws, N);
    k3a_gemm<<<dim3(N/S, 2), 256, 0, stream>>>(beta, posed, shaped, vtemp, RsOut, verts, N);
    k4a_blend<<<(N*195 + 255)/256, 256, 0, stream>>>(Aws, wts, verts, N);
    k4b_joints<<<(N*64 + 255)/256, 256, 0, stream>>>(verts, Jreg, jpart, N);
    k5_joint_sum<<<(N*48 + 255)/256, 256, 0, stream>>>(jpart, joints, N);
}

// Round 13
// 173.144 us; speedup vs baseline: 1.1012x; 1.0149x over previous
//
#include <hip/hip_runtime.h>
#include <math.h>

#define NJ 16
#define NV 778
#define M3 2334   // NV*3
#define S  16     // samples per block in k3a

typedef float f32x16 __attribute__((ext_vector_type(16)));

__device__ __forceinline__ f32x16 splat16(float x) {
    f32x16 r;
#pragma unroll
    for (int i = 0; i < 16; ++i) r[i] = x;
    return r;
}
// elementwise fused r = f*s + c (all constant indices -> pure SSA)
__device__ __forceinline__ f32x16 fma16v(f32x16 f, float s, f32x16 c) {
    f32x16 r;
    r[0]  = fmaf(f[0],  s, c[0]);  r[1]  = fmaf(f[1],  s, c[1]);
    r[2]  = fmaf(f[2],  s, c[2]);  r[3]  = fmaf(f[3],  s, c[3]);
    r[4]  = fmaf(f[4],  s, c[4]);  r[5]  = fmaf(f[5],  s, c[5]);
    r[6]  = fmaf(f[6],  s, c[6]);  r[7]  = fmaf(f[7],  s, c[7]);
    r[8]  = fmaf(f[8],  s, c[8]);  r[9]  = fmaf(f[9],  s, c[9]);
    r[10] = fmaf(f[10], s, c[10]); r[11] = fmaf(f[11], s, c[11]);
    r[12] = fmaf(f[12], s, c[12]); r[13] = fmaf(f[13], s, c[13]);
    r[14] = fmaf(f[14], s, c[14]); r[15] = fmaf(f[15], s, c[15]);
    return r;
}

// d_out layout (floats): verts [N*2334] | joints [N*48] | Rs [N*144]
// d_ws layout (floats):  A [N*192] | jpart [N*4*48]
// Pipeline: k0 -> k1 -> k2(A->ws) -> k3a(v_posed->verts, S=16) ->
//           k4a(blend in place, 2 verts/thread) -> k4b(joint partials) -> k5
//
// LAUNCH-BOUNDS LESSON (R4, R8): second arg w caps VGPR at 256/w -> only (B,1).
// LATENCY LESSON (R9-R12): maximize FMA-per-loaded-float (k3a: 16) and keep
// VGPR moderate so waves/SIMD stay >=5 (k4a R12: 204 VGPR -> 9% occ -> slow).

// ---------------- K0: SJ[b,j,c] = sum_v shapedirs[b,v,c]*Jreg[v,j]; b==10 -> vtemp
__global__ __launch_bounds__(64) void k0_prep(
    const float* __restrict__ shapedirs,
    const float* __restrict__ Jreg,
    const float* __restrict__ vtemp,
    float* __restrict__ SJJT)   // 528 floats
{
    int b = blockIdx.x / 16;    // 0..9 = shapedirs row, 10 = vtemp
    int j = blockIdx.x % 16;
    int t = threadIdx.x;
    const float* src = (b < 10) ? (shapedirs + (size_t)b * M3) : vtemp;
    float a0 = 0.f, a1 = 0.f, a2 = 0.f;
    for (int v = t; v < NV; v += 64) {
        float jr = Jreg[v * 16 + j];
        a0 = fmaf(src[v*3 + 0], jr, a0);
        a1 = fmaf(src[v*3 + 1], jr, a1);
        a2 = fmaf(src[v*3 + 2], jr, a2);
    }
#pragma unroll
    for (int m = 1; m < 64; m <<= 1) {
        a0 += __shfl_xor(a0, m);
        a1 += __shfl_xor(a1, m);
        a2 += __shfl_xor(a2, m);
    }
    if (t == 0) {
        int base = (b < 10) ? (b*48 + j*3) : (480 + j*3);
        SJJT[base + 0] = a0;
        SJJT[base + 1] = a1;
        SJJT[base + 2] = a2;
    }
}

// ---------------- K1: Rodrigues, one thread per (n, joint)
__global__ __launch_bounds__(256) void k1_rodrigues(
    const float* __restrict__ theta, float* __restrict__ RsOut, int N)
{
    int idx = blockIdx.x * 256 + threadIdx.x;
    if (idx >= N * NJ) return;
    int n = idx >> 4;
    int j = idx & 15;
    float t0 = theta[n*48 + j*3 + 0];
    float t1 = theta[n*48 + j*3 + 1];
    float t2 = theta[n*48 + j*3 + 2];
    const float eps = 1e-8f;
    float a0 = t0 + eps, a1 = t1 + eps, a2 = t2 + eps;
    float angle = sqrtf(a0*a0 + a1*a1 + a2*a2);
    float inv  = 1.0f / angle;
    float half = 0.5f * angle;
    float sh = sinf(half), chh = cosf(half);
    float qw = chh;
    float qx = sh * t0 * inv;
    float qy = sh * t1 * inv;
    float qz = sh * t2 * inv;
    float qn = 1.0f / sqrtf(qw*qw + qx*qx + qy*qy + qz*qz);
    qw *= qn; qx *= qn; qy *= qn; qz *= qn;
    float w2=qw*qw, x2=qx*qx, y2=qy*qy, z2=qz*qz;
    float wx=qw*qx, wy=qw*qy, wz=qw*qz;
    float xy=qx*qy, xz=qx*qz, yz=qy*qz;
    float* R = RsOut + (size_t)idx * 9;
    R[0] = w2 + x2 - y2 - z2;
    R[1] = 2.f*(xy - wz);
    R[2] = 2.f*(wy + xz);
    R[3] = 2.f*(wz + xy);
    R[4] = w2 - x2 + y2 - z2;
    R[5] = 2.f*(yz - wx);
    R[6] = 2.f*(xz - wy);
    R[7] = 2.f*(wx + yz);
    R[8] = w2 - x2 - y2 + z2;
}

// ---------------- K2: kinematic chain -> A into d_ws (192 floats / sample)
__global__ __launch_bounds__(64) void k2_chain(
    const float* __restrict__ beta,
    const float* __restrict__ Rs,     // d_out Rs region
    const float* __restrict__ SJJT,   // 528 floats
    float* __restrict__ Aws,          // d_ws; A[n] at n*192
    int N)
{
    __shared__ float sS[528];
    for (int i = threadIdx.x; i < 528; i += 64) sS[i] = SJJT[i];
    __syncthreads();
    int gid = blockIdx.x * 64 + threadIdx.x;
    if (gid >= N * 5) return;
    int n  = gid / 5;
    int ch = gid % 5;

    float b[10];
#pragma unroll
    for (int i = 0; i < 10; ++i) b[i] = beta[n*10 + i];

    int jidx[4];
    jidx[0] = 0; jidx[1] = ch*3 + 1; jidx[2] = ch*3 + 2; jidx[3] = ch*3 + 3;
    float J[4][3];
#pragma unroll
    for (int q = 0; q < 4; ++q) {
        int j = jidx[q];
#pragma unroll
        for (int c = 0; c < 3; ++c) {
            float acc = sS[480 + j*3 + c];
#pragma unroll
            for (int qq = 0; qq < 10; ++qq)
                acc = fmaf(b[qq], sS[qq*48 + j*3 + c], acc);
            J[q][c] = acc;
        }
    }

    const float* Rn = Rs + (size_t)n * 144;
    float* An = Aws + (size_t)n * 192;

    float GpR[9], Gpt[3];
#pragma unroll
    for (int r = 0; r < 3; ++r) {
        GpR[r*3+0] =  Rn[r*3+0];
        GpR[r*3+1] = -Rn[r*3+1];
        GpR[r*3+2] = -Rn[r*3+2];
    }
    Gpt[0] = J[0][0]; Gpt[1] = J[0][1]; Gpt[2] = J[0][2];

    if (ch == 0) {
#pragma unroll
        for (int r = 0; r < 3; ++r) {
            float rel = GpR[r*3+0]*J[0][0] + GpR[r*3+1]*J[0][1] + GpR[r*3+2]*J[0][2];
            An[r*4 + 0] = GpR[r*3+0];
            An[r*4 + 1] = GpR[r*3+1];
            An[r*4 + 2] = GpR[r*3+2];
            An[r*4 + 3] = Gpt[r] - rel;
        }
    }

#pragma unroll
    for (int st = 0; st < 3; ++st) {
        int i = jidx[st+1];
        const float* Ri = Rn + (size_t)i * 9;
        float t0 = J[st+1][0] - J[st][0];
        float t1 = J[st+1][1] - J[st][1];
        float t2 = J[st+1][2] - J[st][2];
        float GR[9], Gt[3];
#pragma unroll
        for (int r = 0; r < 3; ++r) {
#pragma unroll
            for (int c = 0; c < 3; ++c)
                GR[r*3+c] = GpR[r*3+0]*Ri[c] + GpR[r*3+1]*Ri[3+c] + GpR[r*3+2]*Ri[6+c];
            Gt[r] = GpR[r*3+0]*t0 + GpR[r*3+1]*t1 + GpR[r*3+2]*t2 + Gpt[r];
        }
#pragma unroll
        for (int r = 0; r < 3; ++r) {
            float rel = GR[r*3+0]*J[st+1][0] + GR[r*3+1]*J[st+1][1] + GR[r*3+2]*J[st+1][2];
            An[i*12 + r*4 + 0] = GR[r*3+0];
            An[i*12 + r*4 + 1] = GR[r*3+1];
            An[i*12 + r*4 + 2] = GR[r*3+2];
            An[i*12 + r*4 + 3] = Gt[r] - rel;
        }
#pragma unroll
        for (int r = 0; r < 9; ++r) GpR[r] = GR[r];
        Gpt[0] = Gt[0]; Gpt[1] = Gt[1]; Gpt[2] = Gt[2];
    }
}

// ---------------- K3a: GEMM. Block = 16 samples x 256-vert quarter; 1 vert per
// thread, acc = 3 f32x16 = 48 VGPR. Each GSTEP: 3 loaded floats feed 48 FMA
// (16 FMA/float). grid (N/16, 4) = 1024 blocks. Clamped verts >= NV write
// identical redundant values (benign).
#define GSTEP16(rowptr, fk) { \
    f32x16 fv_ = *(const f32x16*)&sF[(fk)][0]; \
    const float* r_ = (rowptr) + 3*vc; \
    float x_ = r_[0], y_ = r_[1], z_ = r_[2]; \
    ax = fma16v(fv_, x_, ax); \
    ay = fma16v(fv_, y_, ay); \
    az = fma16v(fv_, z_, az); }

__global__ __launch_bounds__(256, 1) void k3a_gemm(
    const float* __restrict__ beta,
    const float* __restrict__ posedirs,
    const float* __restrict__ shapedirs,
    const float* __restrict__ vtemp,
    const float* __restrict__ Rs,
    float* __restrict__ vposed,         // verts region
    int N)
{
    __shared__ __attribute__((aligned(64))) float sF[145][S]; // 10 beta + 135 posefeat
    const int n0  = blockIdx.x * S;
    const int tid = threadIdx.x;

    // stage features: k<10 -> beta[k]; k>=10 -> Rs[9 + (k-10)] - I
    for (int idx = tid; idx < 145 * S; idx += 256) {
        int k = idx / S, s = idx % S;
        float val;
        if (k < 10) {
            val = beta[(size_t)(n0+s)*10 + k];
        } else {
            int kk = k - 10;
            int rr = kk % 9;
            val = Rs[(size_t)(n0+s)*144 + 9 + kk];
            if ((rr & 3) == 0) val -= 1.f;   // rr in {0,4,8}
        }
        sF[k][s] = val;
    }
    __syncthreads();

    const int v  = blockIdx.y * 256 + tid;      // 0..1023
    const int vc = (v < NV) ? v : (NV - 1);     // clamp: no divergence

    f32x16 ax = splat16(vtemp[vc*3+0]);
    f32x16 ay = splat16(vtemp[vc*3+1]);
    f32x16 az = splat16(vtemp[vc*3+2]);

    for (int k = 0; k < 10; ++k)  { GSTEP16(shapedirs + (size_t)k*M3, k) }
    for (int k = 0; k < 135; ++k) { GSTEP16(posedirs  + (size_t)k*M3, k + 10) }

#pragma unroll
    for (int s = 0; s < S; ++s) {
        float* o = vposed + (size_t)(n0 + s)*M3 + (size_t)vc*3;
        o[0] = ax[s]; o[1] = ay[s]; o[2] = az[s];
    }
}

// ---------------- K4a: LBS blend, barrier-free, 2 verts per thread (same n).
// 778 = 2*389 exactly -> no tail guard. Regs: w 32 + acc 6 + pos 6 + A-round
// 12 + addr ~= 70 -> >=5 waves/SIMD with 6224 blocks; per j-round 3 uniform
// A loads cover 24 FMA.
__global__ __launch_bounds__(256, 1) void k4a_blend(
    const float* __restrict__ Aws,      // d_ws
    const float* __restrict__ weights,
    float* verts,                       // in-place
    int N)
{
    const int NQ = 389;                 // 778/2
    int gid = blockIdx.x * 256 + threadIdx.x;
    if (gid >= N * NQ) return;
    int n = gid / NQ;
    int q = gid - n * NQ;
    int vb = q * 2;

    float* vp = verts + (size_t)n * M3 + (size_t)vb * 3;   // 8B-aligned
    const float2* vp2 = reinterpret_cast<const float2*>(vp);
    float2 p0 = vp2[0], p1 = vp2[1], p2 = vp2[2];
    float x0 = p0.x, y0 = p0.y, z0 = p1.x;
    float x1 = p1.y, y1 = p2.x, z1 = p2.y;

    f32x16 w0 = *reinterpret_cast<const f32x16*>(&weights[(size_t)vb * 16]);
    f32x16 w1 = *reinterpret_cast<const f32x16*>(&weights[(size_t)(vb+1) * 16]);

    const float4* A4 = reinterpret_cast<const float4*>(Aws + (size_t)n * 192);

    float o0x=0.f,o0y=0.f,o0z=0.f, o1x=0.f,o1y=0.f,o1z=0.f;

#define BJA2(j_) { \
    float4 A0 = A4[(j_)*3+0], A1 = A4[(j_)*3+1], A2 = A4[(j_)*3+2]; \
    float X,Y,Z; \
    X = fmaf(A0.x,x0, fmaf(A0.y,y0, fmaf(A0.z,z0, A0.w))); \
    Y = fmaf(A1.x,x0, fmaf(A1.y,y0, fmaf(A1.z,z0, A1.w))); \
    Z = fmaf(A2.x,x0, fmaf(A2.y,y0, fmaf(A2.z,z0, A2.w))); \
    o0x = fmaf(w0[j_], X, o0x); o0y = fmaf(w0[j_], Y, o0y); o0z = fmaf(w0[j_], Z, o0z); \
    X = fmaf(A0.x,x1, fmaf(A0.y,y1, fmaf(A0.z,z1, A0.w))); \
    Y = fmaf(A1.x,x1, fmaf(A1.y,y1, fmaf(A1.z,z1, A1.w))); \
    Z = fmaf(A2.x,x1, fmaf(A2.y,y1, fmaf(A2.z,z1, A2.w))); \
    o1x = fmaf(w1[j_], X, o1x); o1y = fmaf(w1[j_], Y, o1y); o1z = fmaf(w1[j_], Z, o1z); }

    BJA2(0)  BJA2(1)  BJA2(2)  BJA2(3)  BJA2(4)  BJA2(5)  BJA2(6)  BJA2(7)
    BJA2(8)  BJA2(9)  BJA2(10) BJA2(11) BJA2(12) BJA2(13) BJA2(14) BJA2(15)
#undef BJA2

    float2* op2 = reinterpret_cast<float2*>(vp);
    float2 q0; q0.x = o0x; q0.y = o0y;
    float2 q1; q1.x = o0z; q1.y = o1x;
    float2 q2; q2.x = o1y; q2.y = o1z;
    op2[0] = q0; op2[1] = q1; op2[2] = q2;
}

// ---------------- K4b: joint partials, barrier-free. One thread per
// (n, chunk, j), j fastest (coalesced Jreg; verts broadcast across j-lanes).
__global__ __launch_bounds__(256, 1) void k4b_joints(
    const float* __restrict__ verts,
    const float* __restrict__ Jreg,
    float* __restrict__ jpart,          // d_ws + N*192
    int N)
{
    int gid = blockIdx.x * 256 + threadIdx.x;   // total N*4*16
    if (gid >= N * 64) return;
    int j  = gid & 15;
    int c4 = (gid >> 4) & 3;
    int n  = gid >> 6;

    int vbeg = c4 * 195;
    int vend = vbeg + 195; if (vend > NV) vend = NV;

    const float* vp = verts + (size_t)n * M3;
    float a0 = 0.f, a1 = 0.f, a2 = 0.f;
#pragma unroll 4
    for (int v = vbeg; v < vend; ++v) {
        float jr = Jreg[(size_t)v * 16 + j];
        float x = vp[v*3 + 0], y = vp[v*3 + 1], z = vp[v*3 + 2];
        a0 = fmaf(jr, x, a0);
        a1 = fmaf(jr, y, a1);
        a2 = fmaf(jr, z, a2);
    }
    float* o = jpart + (size_t)n * 192 + c4 * 48 + j * 3;
    o[0] = a0; o[1] = a1; o[2] = a2;
}

// ---------------- K5: joints[n*48+r] = sum_c4 jpart[n*192 + c4*48 + r]
__global__ __launch_bounds__(256) void k5_joint_sum(
    const float* __restrict__ jpart, float* __restrict__ joints, int N)
{
    int i = blockIdx.x * 256 + threadIdx.x;     // N*48
    if (i >= N * 48) return;
    int n = i / 48;
    int r = i - n * 48;
    const float* p = jpart + (size_t)n * 192 + r;
    joints[i] = p[0] + p[48] + p[96] + p[144];
}

extern "C" void kernel_launch(void* const* d_in, const int* in_sizes, int n_in,
                              void* d_out, int out_size, void* d_ws, size_t ws_size,
                              hipStream_t stream)
{
    const float* beta   = (const float*)d_in[0];
    const float* theta  = (const float*)d_in[1];
    const float* vtemp  = (const float*)d_in[2];
    const float* shaped = (const float*)d_in[3];
    const float* Jreg   = (const float*)d_in[4];
    const float* posed  = (const float*)d_in[5];
    const float* wts    = (const float*)d_in[6];
    float* out = (float*)d_out;
    const int N = in_sizes[0] / 10;   // 4096

    float* verts  = out;                            // N*2334
    float* joints = out + (size_t)N * M3;           // N*48
    float* RsOut  = joints + (size_t)N * 48;        // N*144
    float* Aws    = (float*)d_ws;                   // N*192 floats = 3.1 MB
    float* jpart  = Aws + (size_t)N * 192;          // N*192 floats = 3.1 MB

    k0_prep<<<176, 64, 0, stream>>>(shaped, Jreg, vtemp, joints);
    k1_rodrigues<<<(N*NJ + 255)/256, 256, 0, stream>>>(theta, RsOut, N);
    k2_chain<<<(N*5 + 63)/64, 64, 0, stream>>>(beta, RsOut, joints, Aws, N);
    k3a_gemm<<<dim3(N/S, 4), 256, 0, stream>>>(beta, posed, shaped, vtemp, RsOut, verts, N);
    k4a_blend<<<(N*389 + 255)/256, 256, 0, stream>>>(Aws, wts, verts, N);
    k4b_joints<<<(N*64 + 255)/256, 256, 0, stream>>>(verts, Jreg, jpart, N);
    k5_joint_sum<<<(N*48 + 255)/256, 256, 0, stream>>>(jpart, joints, N);
}

// Round 14
// 145.317 us; speedup vs baseline: 1.3120x; 1.1915x over previous
//
#include <hip/hip_runtime.h>
#include <math.h>

#define NJ 16
#define NV 778
#define M3 2334   // NV*3
#define S  16     // samples per block in k3a

typedef float f32x16 __attribute__((ext_vector_type(16)));

__device__ __forceinline__ f32x16 splat16(float x) {
    f32x16 r;
#pragma unroll
    for (int i = 0; i < 16; ++i) r[i] = x;
    return r;
}
// elementwise fused r = f*s + c (all constant indices -> pure SSA)
__device__ __forceinline__ f32x16 fma16v(f32x16 f, float s, f32x16 c) {
    f32x16 r;
    r[0]  = fmaf(f[0],  s, c[0]);  r[1]  = fmaf(f[1],  s, c[1]);
    r[2]  = fmaf(f[2],  s, c[2]);  r[3]  = fmaf(f[3],  s, c[3]);
    r[4]  = fmaf(f[4],  s, c[4]);  r[5]  = fmaf(f[5],  s, c[5]);
    r[6]  = fmaf(f[6],  s, c[6]);  r[7]  = fmaf(f[7],  s, c[7]);
    r[8]  = fmaf(f[8],  s, c[8]);  r[9]  = fmaf(f[9],  s, c[9]);
    r[10] = fmaf(f[10], s, c[10]); r[11] = fmaf(f[11], s, c[11]);
    r[12] = fmaf(f[12], s, c[12]); r[13] = fmaf(f[13], s, c[13]);
    r[14] = fmaf(f[14], s, c[14]); r[15] = fmaf(f[15], s, c[15]);
    return r;
}

// d_out layout (floats): verts [N*2334] | joints [N*48] | Rs [N*144]
// d_ws layout (floats):  A [N*192] | jpart [N*4*48]
// Pipeline: k0 -> k1 -> k2(A->ws) -> k3a(v_posed->verts, S=16) ->
//           k4a(blend in place, A staged in LDS) -> k4b(joint partials) -> k5
//
// LAUNCH-BOUNDS LESSON (R4, R8): second arg w caps VGPR at 256/w -> only (B,1).
// LATENCY LESSONS (R9-R13): (a) per-sample multi-barrier blocks serialize;
// (b) dependent per-thread L2 load chains (A in k4a) cannot be amortized by
// more verts/thread -- the fix is LDS staging (one barrier, broadcast reads).

// ---------------- K0: SJ[b,j,c] = sum_v shapedirs[b,v,c]*Jreg[v,j]; b==10 -> vtemp
__global__ __launch_bounds__(64) void k0_prep(
    const float* __restrict__ shapedirs,
    const float* __restrict__ Jreg,
    const float* __restrict__ vtemp,
    float* __restrict__ SJJT)   // 528 floats
{
    int b = blockIdx.x / 16;    // 0..9 = shapedirs row, 10 = vtemp
    int j = blockIdx.x % 16;
    int t = threadIdx.x;
    const float* src = (b < 10) ? (shapedirs + (size_t)b * M3) : vtemp;
    float a0 = 0.f, a1 = 0.f, a2 = 0.f;
    for (int v = t; v < NV; v += 64) {
        float jr = Jreg[v * 16 + j];
        a0 = fmaf(src[v*3 + 0], jr, a0);
        a1 = fmaf(src[v*3 + 1], jr, a1);
        a2 = fmaf(src[v*3 + 2], jr, a2);
    }
#pragma unroll
    for (int m = 1; m < 64; m <<= 1) {
        a0 += __shfl_xor(a0, m);
        a1 += __shfl_xor(a1, m);
        a2 += __shfl_xor(a2, m);
    }
    if (t == 0) {
        int base = (b < 10) ? (b*48 + j*3) : (480 + j*3);
        SJJT[base + 0] = a0;
        SJJT[base + 1] = a1;
        SJJT[base + 2] = a2;
    }
}

// ---------------- K1: Rodrigues, one thread per (n, joint)
__global__ __launch_bounds__(256) void k1_rodrigues(
    const float* __restrict__ theta, float* __restrict__ RsOut, int N)
{
    int idx = blockIdx.x * 256 + threadIdx.x;
    if (idx >= N * NJ) return;
    int n = idx >> 4;
    int j = idx & 15;
    float t0 = theta[n*48 + j*3 + 0];
    float t1 = theta[n*48 + j*3 + 1];
    float t2 = theta[n*48 + j*3 + 2];
    const float eps = 1e-8f;
    float a0 = t0 + eps, a1 = t1 + eps, a2 = t2 + eps;
    float angle = sqrtf(a0*a0 + a1*a1 + a2*a2);
    float inv  = 1.0f / angle;
    float half = 0.5f * angle;
    float sh = sinf(half), chh = cosf(half);
    float qw = chh;
    float qx = sh * t0 * inv;
    float qy = sh * t1 * inv;
    float qz = sh * t2 * inv;
    float qn = 1.0f / sqrtf(qw*qw + qx*qx + qy*qy + qz*qz);
    qw *= qn; qx *= qn; qy *= qn; qz *= qn;
    float w2=qw*qw, x2=qx*qx, y2=qy*qy, z2=qz*qz;
    float wx=qw*qx, wy=qw*qy, wz=qw*qz;
    float xy=qx*qy, xz=qx*qz, yz=qy*qz;
    float* R = RsOut + (size_t)idx * 9;
    R[0] = w2 + x2 - y2 - z2;
    R[1] = 2.f*(xy - wz);
    R[2] = 2.f*(wy + xz);
    R[3] = 2.f*(wz + xy);
    R[4] = w2 - x2 + y2 - z2;
    R[5] = 2.f*(yz - wx);
    R[6] = 2.f*(xz - wy);
    R[7] = 2.f*(wx + yz);
    R[8] = w2 - x2 - y2 + z2;
}

// ---------------- K2: kinematic chain -> A into d_ws (192 floats / sample)
__global__ __launch_bounds__(64) void k2_chain(
    const float* __restrict__ beta,
    const float* __restrict__ Rs,     // d_out Rs region
    const float* __restrict__ SJJT,   // 528 floats
    float* __restrict__ Aws,          // d_ws; A[n] at n*192
    int N)
{
    __shared__ float sS[528];
    for (int i = threadIdx.x; i < 528; i += 64) sS[i] = SJJT[i];
    __syncthreads();
    int gid = blockIdx.x * 64 + threadIdx.x;
    if (gid >= N * 5) return;
    int n  = gid / 5;
    int ch = gid % 5;

    float b[10];
#pragma unroll
    for (int i = 0; i < 10; ++i) b[i] = beta[n*10 + i];

    int jidx[4];
    jidx[0] = 0; jidx[1] = ch*3 + 1; jidx[2] = ch*3 + 2; jidx[3] = ch*3 + 3;
    float J[4][3];
#pragma unroll
    for (int q = 0; q < 4; ++q) {
        int j = jidx[q];
#pragma unroll
        for (int c = 0; c < 3; ++c) {
            float acc = sS[480 + j*3 + c];
#pragma unroll
            for (int qq = 0; qq < 10; ++qq)
                acc = fmaf(b[qq], sS[qq*48 + j*3 + c], acc);
            J[q][c] = acc;
        }
    }

    const float* Rn = Rs + (size_t)n * 144;
    float* An = Aws + (size_t)n * 192;

    float GpR[9], Gpt[3];
#pragma unroll
    for (int r = 0; r < 3; ++r) {
        GpR[r*3+0] =  Rn[r*3+0];
        GpR[r*3+1] = -Rn[r*3+1];
        GpR[r*3+2] = -Rn[r*3+2];
    }
    Gpt[0] = J[0][0]; Gpt[1] = J[0][1]; Gpt[2] = J[0][2];

    if (ch == 0) {
#pragma unroll
        for (int r = 0; r < 3; ++r) {
            float rel = GpR[r*3+0]*J[0][0] + GpR[r*3+1]*J[0][1] + GpR[r*3+2]*J[0][2];
            An[r*4 + 0] = GpR[r*3+0];
            An[r*4 + 1] = GpR[r*3+1];
            An[r*4 + 2] = GpR[r*3+2];
            An[r*4 + 3] = Gpt[r] - rel;
        }
    }

#pragma unroll
    for (int st = 0; st < 3; ++st) {
        int i = jidx[st+1];
        const float* Ri = Rn + (size_t)i * 9;
        float t0 = J[st+1][0] - J[st][0];
        float t1 = J[st+1][1] - J[st][1];
        float t2 = J[st+1][2] - J[st][2];
        float GR[9], Gt[3];
#pragma unroll
        for (int r = 0; r < 3; ++r) {
#pragma unroll
            for (int c = 0; c < 3; ++c)
                GR[r*3+c] = GpR[r*3+0]*Ri[c] + GpR[r*3+1]*Ri[3+c] + GpR[r*3+2]*Ri[6+c];
            Gt[r] = GpR[r*3+0]*t0 + GpR[r*3+1]*t1 + GpR[r*3+2]*t2 + Gpt[r];
        }
#pragma unroll
        for (int r = 0; r < 3; ++r) {
            float rel = GR[r*3+0]*J[st+1][0] + GR[r*3+1]*J[st+1][1] + GR[r*3+2]*J[st+1][2];
            An[i*12 + r*4 + 0] = GR[r*3+0];
            An[i*12 + r*4 + 1] = GR[r*3+1];
            An[i*12 + r*4 + 2] = GR[r*3+2];
            An[i*12 + r*4 + 3] = Gt[r] - rel;
        }
#pragma unroll
        for (int r = 0; r < 9; ++r) GpR[r] = GR[r];
        Gpt[0] = Gt[0]; Gpt[1] = Gt[1]; Gpt[2] = Gt[2];
    }
}

// ---------------- K3a: GEMM. Block = 16 samples x 256-vert quarter; 1 vert per
// thread, acc = 3 f32x16 = 48 VGPR. Each GSTEP: 3 loaded floats feed 48 FMA.
#define GSTEP16(rowptr, fk) { \
    f32x16 fv_ = *(const f32x16*)&sF[(fk)][0]; \
    const float* r_ = (rowptr) + 3*vc; \
    float x_ = r_[0], y_ = r_[1], z_ = r_[2]; \
    ax = fma16v(fv_, x_, ax); \
    ay = fma16v(fv_, y_, ay); \
    az = fma16v(fv_, z_, az); }

__global__ __launch_bounds__(256, 1) void k3a_gemm(
    const float* __restrict__ beta,
    const float* __restrict__ posedirs,
    const float* __restrict__ shapedirs,
    const float* __restrict__ vtemp,
    const float* __restrict__ Rs,
    float* __restrict__ vposed,         // verts region
    int N)
{
    __shared__ __attribute__((aligned(64))) float sF[145][S]; // 10 beta + 135 posefeat
    const int n0  = blockIdx.x * S;
    const int tid = threadIdx.x;

    // stage features: k<10 -> beta[k]; k>=10 -> Rs[9 + (k-10)] - I
    for (int idx = tid; idx < 145 * S; idx += 256) {
        int k = idx / S, s = idx % S;
        float val;
        if (k < 10) {
            val = beta[(size_t)(n0+s)*10 + k];
        } else {
            int kk = k - 10;
            int rr = kk % 9;
            val = Rs[(size_t)(n0+s)*144 + 9 + kk];
            if ((rr & 3) == 0) val -= 1.f;   // rr in {0,4,8}
        }
        sF[k][s] = val;
    }
    __syncthreads();

    const int v  = blockIdx.y * 256 + tid;      // 0..1023
    const int vc = (v < NV) ? v : (NV - 1);     // clamp: no divergence

    f32x16 ax = splat16(vtemp[vc*3+0]);
    f32x16 ay = splat16(vtemp[vc*3+1]);
    f32x16 az = splat16(vtemp[vc*3+2]);

    for (int k = 0; k < 10; ++k)  { GSTEP16(shapedirs + (size_t)k*M3, k) }
    for (int k = 0; k < 135; ++k) { GSTEP16(posedirs  + (size_t)k*M3, k + 10) }

#pragma unroll
    for (int s = 0; s < S; ++s) {
        float* o = vposed + (size_t)(n0 + s)*M3 + (size_t)vc*3;
        o[0] = ax[s]; o[1] = ay[s]; o[2] = az[s];
    }
}

// ---------------- K4a: LBS blend, A staged in LDS (kills the L2 dependent
// chain). grid (N, 2): q=0 -> verts 0..511, q=1 -> 512..777. 2 verts/thread.
// Global loads issued BEFORE the barrier so HBM latency hides under staging.
__global__ __launch_bounds__(256, 1) void k4a_blend(
    const float* __restrict__ Aws,      // d_ws
    const float* __restrict__ weights,
    float* verts,                       // in-place
    int N)
{
    __shared__ __attribute__((aligned(16))) float4 sA4[48];
    const int n   = blockIdx.x;
    const int q   = blockIdx.y;
    const int tid = threadIdx.x;

    if (tid < 48) sA4[tid] = reinterpret_cast<const float4*>(Aws + (size_t)n * 192)[tid];

    const int v0 = q * 512 + tid;               // always < 778
    const int v1 = v0 + 256;                    // q=1: 768..1023 -> guard
    const bool m1 = v1 < NV;
    const int c1 = m1 ? v1 : (NV - 1);

    float* vp0 = verts + (size_t)n * M3 + (size_t)v0 * 3;
    float* vp1 = verts + (size_t)n * M3 + (size_t)c1 * 3;
    float x0 = vp0[0], y0 = vp0[1], z0 = vp0[2];
    float x1 = vp1[0], y1 = vp1[1], z1 = vp1[2];
    f32x16 w0 = *reinterpret_cast<const f32x16*>(&weights[(size_t)v0 * 16]);
    f32x16 w1 = *reinterpret_cast<const f32x16*>(&weights[(size_t)c1 * 16]);

    __syncthreads();   // sA4 ready

    float o0x=0.f,o0y=0.f,o0z=0.f, o1x=0.f,o1y=0.f,o1z=0.f;

#define BJA2(j_) { \
    float4 A0 = sA4[(j_)*3+0], A1 = sA4[(j_)*3+1], A2 = sA4[(j_)*3+2]; \
    float X,Y,Z; \
    X = fmaf(A0.x,x0, fmaf(A0.y,y0, fmaf(A0.z,z0, A0.w))); \
    Y = fmaf(A1.x,x0, fmaf(A1.y,y0, fmaf(A1.z,z0, A1.w))); \
    Z = fmaf(A2.x,x0, fmaf(A2.y,y0, fmaf(A2.z,z0, A2.w))); \
    o0x = fmaf(w0[j_], X, o0x); o0y = fmaf(w0[j_], Y, o0y); o0z = fmaf(w0[j_], Z, o0z); \
    X = fmaf(A0.x,x1, fmaf(A0.y,y1, fmaf(A0.z,z1, A0.w))); \
    Y = fmaf(A1.x,x1, fmaf(A1.y,y1, fmaf(A1.z,z1, A1.w))); \
    Z = fmaf(A2.x,x1, fmaf(A2.y,y1, fmaf(A2.z,z1, A2.w))); \
    o1x = fmaf(w1[j_], X, o1x); o1y = fmaf(w1[j_], Y, o1y); o1z = fmaf(w1[j_], Z, o1z); }

    BJA2(0)  BJA2(1)  BJA2(2)  BJA2(3)  BJA2(4)  BJA2(5)  BJA2(6)  BJA2(7)
    BJA2(8)  BJA2(9)  BJA2(10) BJA2(11) BJA2(12) BJA2(13) BJA2(14) BJA2(15)
#undef BJA2

    vp0[0] = o0x; vp0[1] = o0y; vp0[2] = o0z;
    if (m1) { vp1[0] = o1x; vp1[1] = o1y; vp1[2] = o1z; }
}

// ---------------- K4b: joint partials, barrier-free. One thread per
// (n, chunk, j), j fastest (coalesced Jreg; verts broadcast across j-lanes).
__global__ __launch_bounds__(256, 1) void k4b_joints(
    const float* __restrict__ verts,
    const float* __restrict__ Jreg,
    float* __restrict__ jpart,          // d_ws + N*192
    int N)
{
    int gid = blockIdx.x * 256 + threadIdx.x;   // total N*4*16
    if (gid >= N * 64) return;
    int j  = gid & 15;
    int c4 = (gid >> 4) & 3;
    int n  = gid >> 6;

    int vbeg = c4 * 195;
    int vend = vbeg + 195; if (vend > NV) vend = NV;

    const float* vp = verts + (size_t)n * M3;
    float a0 = 0.f, a1 = 0.f, a2 = 0.f;
#pragma unroll 4
    for (int v = vbeg; v < vend; ++v) {
        float jr = Jreg[(size_t)v * 16 + j];
        float x = vp[v*3 + 0], y = vp[v*3 + 1], z = vp[v*3 + 2];
        a0 = fmaf(jr, x, a0);
        a1 = fmaf(jr, y, a1);
        a2 = fmaf(jr, z, a2);
    }
    float* o = jpart + (size_t)n * 192 + c4 * 48 + j * 3;
    o[0] = a0; o[1] = a1; o[2] = a2;
}

// ---------------- K5: joints[n*48+r] = sum_c4 jpart[n*192 + c4*48 + r]
__global__ __launch_bounds__(256) void k5_joint_sum(
    const float* __restrict__ jpart, float* __restrict__ joints, int N)
{
    int i = blockIdx.x * 256 + threadIdx.x;     // N*48
    if (i >= N * 48) return;
    int n = i / 48;
    int r = i - n * 48;
    const float* p = jpart + (size_t)n * 192 + r;
    joints[i] = p[0] + p[48] + p[96] + p[144];
}

extern "C" void kernel_launch(void* const* d_in, const int* in_sizes, int n_in,
                              void* d_out, int out_size, void* d_ws, size_t ws_size,
                              hipStream_t stream)
{
    const float* beta   = (const float*)d_in[0];
    const float* theta  = (const float*)d_in[1];
    const float* vtemp  = (const float*)d_in[2];
    const float* shaped = (const float*)d_in[3];
    const float* Jreg   = (const float*)d_in[4];
    const float* posed  = (const float*)d_in[5];
    const float* wts    = (const float*)d_in[6];
    float* out = (float*)d_out;
    const int N = in_sizes[0] / 10;   // 4096

    float* verts  = out;                            // N*2334
    float* joints = out + (size_t)N * M3;           // N*48
    float* RsOut  = joints + (size_t)N * 48;        // N*144
    float* Aws    = (float*)d_ws;                   // N*192 floats = 3.1 MB
    float* jpart  = Aws + (size_t)N * 192;          // N*192 floats = 3.1 MB

    k0_prep<<<176, 64, 0, stream>>>(shaped, Jreg, vtemp, joints);
    k1_rodrigues<<<(N*NJ + 255)/256, 256, 0, stream>>>(theta, RsOut, N);
    k2_chain<<<(N*5 + 63)/64, 64, 0, stream>>>(beta, RsOut, joints, Aws, N);
    k3a_gemm<<<dim3(N/S, 4), 256, 0, stream>>>(beta, posed, shaped, vtemp, RsOut, verts, N);
    k4a_blend<<<dim3(N, 2), 256, 0, stream>>>(Aws, wts, verts, N);
    k4b_joints<<<(N*64 + 255)/256, 256, 0, stream>>>(verts, Jreg, jpart, N);
    k5_joint_sum<<<(N*48 + 255)/256, 256, 0, stream>>>(jpart, joints, N);
}